// Round 7
// baseline (519.169 us; speedup 1.0000x reference)
//
#include <hip/hip_runtime.h>
#include <hip/hip_cooperative_groups.h>

// MIND-SSC loss, N=2, C=1, D=H=W=128, radius=1, dilation=2.
// Round 7: single cooperative kernel (init + fused compute + clip-flag +
// optional clipped fallback + finalize) — removes ~59 us of dispatch overhead
// measured in round 6. Math identical to round 6:
//  - x-folded staging, pred/targ packed float2, y-box from LDS, z-box ring
//  - unclipped loss + var min/max; exact clip-binding test; clipped recompute
//    only if the clip would bind (never does for these inputs)
//  - nested clamps preserved exactly; /27 dropped (exact: scale-invariant)

namespace cg = cooperative_groups;

#define DIM 128
#define HW (128 * 128)
#define DHW (128 * 128 * 128)
#define NVOX (2 * DHW)
#define LOSS_COUNT (2.0 * 12.0 * DHW)

#define TS   16                   // tile side (y and x)
#define SY   18                   // xsum rows incl. y halo
#define NSP  (SY * TS)            // 288 xsum positions
#define CHZ  16                   // z-chunk per block
#define PSTR 7                    // f4 stride per position (6 used + 1 pad)

typedef float f4 __attribute__((ext_vector_type(4)));
typedef float f2 __attribute__((ext_vector_type(2)));

__device__ __forceinline__ int clampi(int v) {
    v = v < 0 ? 0 : v;
    return v > 127 ? 127 : v;
}

__device__ __forceinline__ unsigned fkey(float f) {
    unsigned u = __float_as_uint(f);
    return (u & 0x80000000u) ? ~u : (u | 0x80000000u);
}
__device__ __forceinline__ float fdec(unsigned k) {
    unsigned u = (k & 0x80000000u) ? (k ^ 0x80000000u) : ~k;
    return __uint_as_float(u);
}

__device__ __forceinline__ void block_reduce_atomic(float v, double* dst) {
#pragma unroll
    for (int off = 32; off > 0; off >>= 1)
        v += __shfl_down(v, off, 64);
    __shared__ float red[4];
    int lane = threadIdx.x & 63;
    int wid  = threadIdx.x >> 6;
    if (lane == 0) red[wid] = v;
    __syncthreads();
    if (threadIdx.x == 0) {
        double t = (double)red[0] + (double)red[1] + (double)red[2] + (double)red[3];
        atomicAdd(dst, t);
    }
    __syncthreads();
}

__device__ __forceinline__ void block_minmax_atomic(float mnp, float mxp,
                                                    float mnt, float mxt,
                                                    unsigned* keys) {
#pragma unroll
    for (int off = 32; off > 0; off >>= 1) {
        mnp = fminf(mnp, __shfl_down(mnp, off, 64));
        mxp = fmaxf(mxp, __shfl_down(mxp, off, 64));
        mnt = fminf(mnt, __shfl_down(mnt, off, 64));
        mxt = fmaxf(mxt, __shfl_down(mxt, off, 64));
    }
    __shared__ float r[4][4];
    int lane = threadIdx.x & 63, wid = threadIdx.x >> 6;
    if (lane == 0) { r[wid][0] = mnp; r[wid][1] = mxp; r[wid][2] = mnt; r[wid][3] = mxt; }
    __syncthreads();
    if (threadIdx.x == 0) {
        float a = fminf(fminf(r[0][0], r[1][0]), fminf(r[2][0], r[3][0]));
        float b = fmaxf(fmaxf(r[0][1], r[1][1]), fmaxf(r[2][1], r[3][1]));
        float c = fminf(fminf(r[0][2], r[1][2]), fminf(r[2][2], r[3][2]));
        float d = fmaxf(fmaxf(r[0][3], r[1][3]), fmaxf(r[2][3], r[3][3]));
        atomicMin(&keys[0], fkey(a));
        atomicMax(&keys[1], fkey(b));
        atomicMin(&keys[2], fkey(c));
        atomicMax(&keys[3], fkey(d));
    }
    __syncthreads();
}

struct SPos {
    int y0, ym, yp;          // row offsets * DIM
    int cx[3], cm[3], cp[3]; // per-wx tap columns
    int woff;                // f4 index in LDS
};

__device__ __forceinline__ SPos make_spos(int p, int y0t, int x0t, int stride) {
    SPos q;
    int py = p >> 4, px = p & 15;
    int gy = clampi(y0t - 1 + py);
    int gx = x0t + px;
    q.y0 = gy * DIM; q.ym = clampi(gy - 2) * DIM; q.yp = clampi(gy + 2) * DIM;
#pragma unroll
    for (int wx = 0; wx < 3; ++wx) {
        int c = clampi(gx + wx - 1);   // box tap clamp (outer pad)
        q.cx[wx] = c;
        q.cm[wx] = clampi(c - 2);      // dilation clamp (inner pad)
        q.cp[wx] = clampi(c + 2);
    }
    q.woff = p * stride;
    return q;
}

// xsum for BOTH images at this position (packed f2); writes 6 f4.
__device__ __forceinline__ void stage_pair(const float* __restrict__ ip,
                                           const float* __restrict__ tp,
                                           int zm, int zc, int zp,
                                           const SPos& q, f4* __restrict__ X) {
    // hoisted row bases: 5 adds instead of 36
    const int r0 = zm + q.y0, r1 = zc + q.y0, r2 = zc + q.ym;
    const int r3 = zc + q.yp, r4 = zp + q.y0;
    f2 acc[12];
#pragma unroll
    for (int c = 0; c < 12; ++c) acc[c] = (f2)0.0f;
#pragma unroll
    for (int wx = 0; wx < 3; ++wx) {
        int o0 = r0 + q.cx[wx];
        int o1 = r1 + q.cm[wx];
        int o2 = r2 + q.cx[wx];
        int o3 = r1 + q.cp[wx];
        int o4 = r4 + q.cx[wx];
        int o5 = r3 + q.cx[wx];
        f2 s0 = {ip[o0], tp[o0]};
        f2 s1 = {ip[o1], tp[o1]};
        f2 s2 = {ip[o2], tp[o2]};
        f2 s3 = {ip[o3], tp[o3]};
        f2 s4 = {ip[o4], tp[o4]};
        f2 s5 = {ip[o5], tp[o5]};
        f2 d;
        d = s1 - s0; acc[0]  += d * d;
        d = s2 - s0; acc[1]  += d * d;
        d = s2 - s1; acc[2]  += d * d;
        d = s3 - s0; acc[3]  += d * d;
        d = s3 - s2; acc[4]  += d * d;
        d = s4 - s1; acc[5]  += d * d;
        d = s4 - s2; acc[6]  += d * d;
        d = s4 - s3; acc[7]  += d * d;
        d = s5 - s0; acc[8]  += d * d;
        d = s5 - s1; acc[9]  += d * d;
        d = s5 - s3; acc[10] += d * d;
        d = s5 - s4; acc[11] += d * d;
    }
#pragma unroll
    for (int k = 0; k < 6; ++k) {
        f4 w;
        w.x = acc[2 * k].x;     w.y = acc[2 * k].y;
        w.z = acc[2 * k + 1].x; w.w = acc[2 * k + 1].y;
        X[q.woff + k] = w;
    }
}

__device__ __forceinline__ void box3y_pair(const f4* __restrict__ X,
                                           int ty, int tx, f4 q[6]) {
    int b0 = ((ty + 0) * TS + tx) * PSTR;
    int b1 = ((ty + 1) * TS + tx) * PSTR;
    int b2 = ((ty + 2) * TS + tx) * PSTR;
#pragma unroll
    for (int k = 0; k < 6; ++k)
        q[k] = X[b0 + k] + X[b1 + k] + X[b2 + k];
}

// single-image variants (clipped fallback path)
__device__ __forceinline__ void stage_xsum(const float* __restrict__ im,
                                           int zm, int zc, int zp,
                                           const SPos& q, f4* __restrict__ P) {
    const int r0 = zm + q.y0, r1 = zc + q.y0, r2 = zc + q.ym;
    const int r3 = zc + q.yp, r4 = zp + q.y0;
    f4 a = (f4)0.0f, b = (f4)0.0f, c = (f4)0.0f;
#pragma unroll
    for (int wx = 0; wx < 3; ++wx) {
        float s0 = im[r0 + q.cx[wx]];
        float s1 = im[r1 + q.cm[wx]];
        float s2 = im[r2 + q.cx[wx]];
        float s3 = im[r1 + q.cp[wx]];
        float s4 = im[r4 + q.cx[wx]];
        float s5 = im[r3 + q.cx[wx]];
        float d;
        d = s1 - s0; a.x += d * d;
        d = s2 - s0; a.y += d * d;
        d = s2 - s1; a.z += d * d;
        d = s3 - s0; a.w += d * d;
        d = s3 - s2; b.x += d * d;
        d = s4 - s1; b.y += d * d;
        d = s4 - s2; b.z += d * d;
        d = s4 - s3; b.w += d * d;
        d = s5 - s0; c.x += d * d;
        d = s5 - s1; c.y += d * d;
        d = s5 - s3; c.z += d * d;
        d = s5 - s4; c.w += d * d;
    }
    P[q.woff + 0] = a;
    P[q.woff + 1] = b;
    P[q.woff + 2] = c;
}

__device__ __forceinline__ void box3y(const f4* __restrict__ P,
                                      int ty, int tx, f4 q[3]) {
    int base = (ty * TS + tx) * 3;
#pragma unroll
    for (int k = 0; k < 3; ++k)
        q[k] = P[base + k] + P[base + TS * 3 + k] + P[base + 2 * TS * 3 + k];
}

__device__ __forceinline__ float min12(const f4 v[3]) {
    float mn = v[0][0];
#pragma unroll
    for (int i = 0; i < 4; ++i)
        mn = fminf(mn, fminf(v[0][i], fminf(v[1][i], v[2][i])));
    return mn;
}
__device__ __forceinline__ float sum12(const f4 v[3]) {
    float sm = 0.0f;
#pragma unroll
    for (int i = 0; i < 4; ++i)
        sm += v[0][i] + v[1][i] + v[2][i];
    return sm;
}

// =====================  mono cooperative kernel  ==========================

__global__ __launch_bounds__(256, 4) void mono_kernel(const float* __restrict__ pred,
                                                      const float* __restrict__ targ,
                                                      double* __restrict__ acc,
                                                      unsigned* __restrict__ keys,
                                                      float* __restrict__ out) {
    cg::grid_group grid = cg::this_grid();

    __shared__ f4 X[NSP * PSTR];      // 32256 B; reused by fallback phase

    const int t = threadIdx.x;
    const int tile = blockIdx.x & 63, n = blockIdx.x >> 6;
    const int x0t = (tile & 7) * TS, y0t = (tile >> 3) * TS;
    const int z0 = blockIdx.y * CHZ;
    const float* ip = pred + (size_t)n * DHW;
    const float* tp = targ + (size_t)n * DHW;
    const bool isB0 = (blockIdx.x == 0 && blockIdx.y == 0);

    // ---- phase 0: init accumulators (d_ws is poisoned each call) ----
    if (isB0 && t == 0) {
        acc[0] = 0.0; acc[1] = 0.0; acc[2] = 0.0; acc[3] = 0.0;
        keys[0] = 0xFFFFFFFFu; keys[1] = 0u;
        keys[2] = 0xFFFFFFFFu; keys[3] = 0u;
    }
    grid.sync();

    // ---- phase 1: fused compute (unclipped loss + var sums + var min/max) ----
    SPos pa = make_spos(t, y0t, x0t, PSTR);
    const bool hasB = (t + 256) < NSP;
    SPos pb = make_spos(hasB ? (t + 256) : 0, y0t, x0t, PSTR);
    const int ty = t >> 4, tx = t & 15;

    {
        f4 A[6], B[6];
#pragma unroll
        for (int k = 0; k < 6; ++k) { A[k] = (f4)0.0f; B[k] = (f4)0.0f; }

        float vsump = 0.0f, vsumt = 0.0f, lsum = 0.0f;
        float locmnp = 1e30f, locmxp = -1e30f, locmnt = 1e30f, locmxt = -1e30f;

        for (int tz = z0 - 1; tz <= z0 + CHZ; ++tz) {
            int zq = clampi(tz);
            int zc = zq * HW, zm = clampi(zq - 2) * HW, zp = clampi(zq + 2) * HW;
            stage_pair(ip, tp, zm, zc, zp, pa, X);
            if (hasB) stage_pair(ip, tp, zm, zc, zp, pb, X);
            __syncthreads();

            f4 q[6];
            box3y_pair(X, ty, tx, q);
            __syncthreads();

            int ze = tz - 1;
            if (ze >= z0) {
                f4 v[6];
#pragma unroll
                for (int k = 0; k < 6; ++k) v[k] = A[k] + q[k];

                float mnp = v[0][0], mnt = v[0][1];
                float smp = 0.0f, smt = 0.0f;
#pragma unroll
                for (int c = 0; c < 12; ++c) {
                    float pv = v[c >> 1][(c & 1) * 2];
                    float tv = v[c >> 1][(c & 1) * 2 + 1];
                    mnp = fminf(mnp, pv); smp += pv;
                    mnt = fminf(mnt, tv); smt += tv;
                }
                float varp = smp * (1.0f / 12.0f) - mnp;
                float vart = smt * (1.0f / 12.0f) - mnt;
                vsump += varp; vsumt += vart;
                locmnp = fminf(locmnp, varp); locmxp = fmaxf(locmxp, varp);
                locmnt = fminf(locmnt, vart); locmxt = fmaxf(locmxt, vart);

                float invp = -1.0f / varp;   // unclipped; validated below
                float invt = -1.0f / vart;
                float la = 0.0f;
#pragma unroll
                for (int c = 0; c < 12; ++c) {
                    float pv = v[c >> 1][(c & 1) * 2];
                    float tv = v[c >> 1][(c & 1) * 2 + 1];
                    float ep = __expf((pv - mnp) * invp);
                    float et = __expf((tv - mnt) * invt);
                    float dd = ep - et;
                    la += dd * dd;
                }
                lsum += la;
            }
#pragma unroll
            for (int k = 0; k < 6; ++k) { A[k] = B[k] + q[k]; B[k] = q[k]; }
        }

        block_reduce_atomic(vsump, &acc[0]);
        block_reduce_atomic(vsumt, &acc[1]);
        block_reduce_atomic(lsum,  &acc[2]);
        block_minmax_atomic(locmnp, locmxp, locmnt, locmxt, keys);
    }
    __threadfence();
    grid.sync();

    // ---- phase 2: per-block clip-binding test ----
    __shared__ float s_mp, s_mt;
    __shared__ int s_clean;
    if (t == 0) {
        double a0 = __hip_atomic_load(&acc[0], __ATOMIC_RELAXED, __HIP_MEMORY_SCOPE_AGENT);
        double a1 = __hip_atomic_load(&acc[1], __ATOMIC_RELAXED, __HIP_MEMORY_SCOPE_AGENT);
        unsigned k0 = __hip_atomic_load(&keys[0], __ATOMIC_RELAXED, __HIP_MEMORY_SCOPE_AGENT);
        unsigned k1 = __hip_atomic_load(&keys[1], __ATOMIC_RELAXED, __HIP_MEMORY_SCOPE_AGENT);
        unsigned k2 = __hip_atomic_load(&keys[2], __ATOMIC_RELAXED, __HIP_MEMORY_SCOPE_AGENT);
        unsigned k3 = __hip_atomic_load(&keys[3], __ATOMIC_RELAXED, __HIP_MEMORY_SCOPE_AGENT);
        float m_p = (float)(a0 * (1.0 / (double)NVOX));
        float m_t = (float)(a1 * (1.0 / (double)NVOX));
        // clip leaves v unchanged iff lo <= v <= hi (same fp exprs as fallback)
        bool clean = (fdec(k0) >= m_p * 0.001f) && (fdec(k1) <= m_p * 1000.0f) &&
                     (fdec(k2) >= m_t * 0.001f) && (fdec(k3) <= m_t * 1000.0f);
        s_mp = m_p; s_mt = m_t; s_clean = clean ? 1 : 0;
    }
    __syncthreads();
    const bool clean = (s_clean != 0);
    const float m_p = s_mp, m_t = s_mt;

    // ---- phase 3: clipped recompute only if the clip binds ----
    if (!clean) {
        f4* Xp = X;
        f4* Xt = X + NSP * 3;
        SPos fa = make_spos(t, y0t, x0t, 3);
        SPos fb = make_spos(hasB ? (t + 256) : 0, y0t, x0t, 3);

        f4 Ap[3], Bp[3], At[3], Bt[3];
#pragma unroll
        for (int q = 0; q < 3; ++q) {
            Ap[q] = (f4)0.0f; Bp[q] = (f4)0.0f;
            At[q] = (f4)0.0f; Bt[q] = (f4)0.0f;
        }
        float lsum = 0.0f;

        for (int tz = z0 - 1; tz <= z0 + CHZ; ++tz) {
            int zq = clampi(tz);
            int zc = zq * HW, zm = clampi(zq - 2) * HW, zp = clampi(zq + 2) * HW;
            stage_xsum(ip, zm, zc, zp, fa, Xp);
            stage_xsum(tp, zm, zc, zp, fa, Xt);
            if (hasB) {
                stage_xsum(ip, zm, zc, zp, fb, Xp);
                stage_xsum(tp, zm, zc, zp, fb, Xt);
            }
            __syncthreads();

            f4 qp[3], qt[3];
            box3y(Xp, ty, tx, qp);
            box3y(Xt, ty, tx, qt);
            __syncthreads();

            int ze = tz - 1;
            if (ze >= z0) {
                f4 vp[3], vt[3];
#pragma unroll
                for (int q = 0; q < 3; ++q) {
                    vp[q] = Ap[q] + qp[q];
                    vt[q] = At[q] + qt[q];
                }
                float mnp = min12(vp), smp = sum12(vp);
                float mnt = min12(vt), smt = sum12(vt);
                float varp = smp * (1.0f / 12.0f) - mnp;
                varp = fminf(fmaxf(varp, m_p * 0.001f), m_p * 1000.0f);
                float invp = -1.0f / varp;
                float vart = smt * (1.0f / 12.0f) - mnt;
                vart = fminf(fmaxf(vart, m_t * 0.001f), m_t * 1000.0f);
                float invt = -1.0f / vart;

                float a = 0.0f;
#pragma unroll
                for (int q = 0; q < 3; ++q)
#pragma unroll
                    for (int i = 0; i < 4; ++i) {
                        float ep = __expf((vp[q][i] - mnp) * invp);
                        float et = __expf((vt[q][i] - mnt) * invt);
                        float dd = ep - et;
                        a += dd * dd;
                    }
                lsum += a;
            }
#pragma unroll
            for (int q = 0; q < 3; ++q) {
                Ap[q] = Bp[q] + qp[q]; Bp[q] = qp[q];
                At[q] = Bt[q] + qt[q]; Bt[q] = qt[q];
            }
        }
        block_reduce_atomic(lsum, &acc[3]);
        __threadfence();
    }
    grid.sync();

    // ---- phase 4: finalize ----
    if (isB0 && t == 0) {
        double l = clean
            ? __hip_atomic_load(&acc[2], __ATOMIC_RELAXED, __HIP_MEMORY_SCOPE_AGENT)
            : __hip_atomic_load(&acc[3], __ATOMIC_RELAXED, __HIP_MEMORY_SCOPE_AGENT);
        out[0] = (float)(l * (1.0 / LOSS_COUNT));
    }
}

// =============  fallback multi-kernel path (round-6, if coop fails) ========

__global__ void init_kernel(double* __restrict__ acc, unsigned* __restrict__ keys) {
    acc[0] = 0.0; acc[1] = 0.0; acc[2] = 0.0; acc[3] = 0.0;
    keys[0] = 0xFFFFFFFFu; keys[1] = 0u;
    keys[2] = 0xFFFFFFFFu; keys[3] = 0u;
    keys[4] = 0u;
}

__global__ __launch_bounds__(256, 4) void fused_kernel(const float* __restrict__ pred,
                                                       const float* __restrict__ targ,
                                                       double* __restrict__ acc,
                                                       unsigned* __restrict__ keys) {
    __shared__ f4 X[NSP * PSTR];
    const int t = threadIdx.x;
    const int tile = blockIdx.x & 63, n = blockIdx.x >> 6;
    const int x0t = (tile & 7) * TS, y0t = (tile >> 3) * TS;
    const int z0 = blockIdx.y * CHZ;
    const float* ip = pred + (size_t)n * DHW;
    const float* tp = targ + (size_t)n * DHW;

    SPos pa = make_spos(t, y0t, x0t, PSTR);
    const bool hasB = (t + 256) < NSP;
    SPos pb = make_spos(hasB ? (t + 256) : 0, y0t, x0t, PSTR);
    const int ty = t >> 4, tx = t & 15;

    f4 A[6], B[6];
#pragma unroll
    for (int k = 0; k < 6; ++k) { A[k] = (f4)0.0f; B[k] = (f4)0.0f; }

    float vsump = 0.0f, vsumt = 0.0f, lsum = 0.0f;
    float locmnp = 1e30f, locmxp = -1e30f, locmnt = 1e30f, locmxt = -1e30f;

    for (int tz = z0 - 1; tz <= z0 + CHZ; ++tz) {
        int zq = clampi(tz);
        int zc = zq * HW, zm = clampi(zq - 2) * HW, zp = clampi(zq + 2) * HW;
        stage_pair(ip, tp, zm, zc, zp, pa, X);
        if (hasB) stage_pair(ip, tp, zm, zc, zp, pb, X);
        __syncthreads();

        f4 q[6];
        box3y_pair(X, ty, tx, q);
        __syncthreads();

        int ze = tz - 1;
        if (ze >= z0) {
            f4 v[6];
#pragma unroll
            for (int k = 0; k < 6; ++k) v[k] = A[k] + q[k];
            float mnp = v[0][0], mnt = v[0][1];
            float smp = 0.0f, smt = 0.0f;
#pragma unroll
            for (int c = 0; c < 12; ++c) {
                float pv = v[c >> 1][(c & 1) * 2];
                float tv = v[c >> 1][(c & 1) * 2 + 1];
                mnp = fminf(mnp, pv); smp += pv;
                mnt = fminf(mnt, tv); smt += tv;
            }
            float varp = smp * (1.0f / 12.0f) - mnp;
            float vart = smt * (1.0f / 12.0f) - mnt;
            vsump += varp; vsumt += vart;
            locmnp = fminf(locmnp, varp); locmxp = fmaxf(locmxp, varp);
            locmnt = fminf(locmnt, vart); locmxt = fmaxf(locmxt, vart);
            float invp = -1.0f / varp;
            float invt = -1.0f / vart;
            float la = 0.0f;
#pragma unroll
            for (int c = 0; c < 12; ++c) {
                float pv = v[c >> 1][(c & 1) * 2];
                float tv = v[c >> 1][(c & 1) * 2 + 1];
                float ep = __expf((pv - mnp) * invp);
                float et = __expf((tv - mnt) * invt);
                float dd = ep - et;
                la += dd * dd;
            }
            lsum += la;
        }
#pragma unroll
        for (int k = 0; k < 6; ++k) { A[k] = B[k] + q[k]; B[k] = q[k]; }
    }

    block_reduce_atomic(vsump, &acc[0]);
    block_reduce_atomic(vsumt, &acc[1]);
    block_reduce_atomic(lsum,  &acc[2]);
    block_minmax_atomic(locmnp, locmxp, locmnt, locmxt, keys);
}

__global__ void flag_kernel(const double* __restrict__ acc, unsigned* __restrict__ keys) {
    float m_p = (float)(acc[0] * (1.0 / (double)NVOX));
    float m_t = (float)(acc[1] * (1.0 / (double)NVOX));
    bool clean = (fdec(keys[0]) >= m_p * 0.001f) && (fdec(keys[1]) <= m_p * 1000.0f) &&
                 (fdec(keys[2]) >= m_t * 0.001f) && (fdec(keys[3]) <= m_t * 1000.0f);
    keys[4] = clean ? 0u : 1u;
}

__global__ __launch_bounds__(256, 4) void loss_kernel(const float* __restrict__ pred,
                                                      const float* __restrict__ targ,
                                                      const double* __restrict__ acc,
                                                      const unsigned* __restrict__ keys,
                                                      double* __restrict__ loss_sum) {
    if (keys[4] == 0u) return;

    __shared__ f4 Xp[NSP * 3];
    __shared__ f4 Xt[NSP * 3];
    const int t = threadIdx.x;
    const int tile = blockIdx.x & 63, n = blockIdx.x >> 6;
    const int x0t = (tile & 7) * TS, y0t = (tile >> 3) * TS;
    const int z0 = blockIdx.y * CHZ;
    const float* ip = pred + (size_t)n * DHW;
    const float* tp = targ + (size_t)n * DHW;

    const float m_p = (float)(acc[0] * (1.0 / (double)NVOX));
    const float m_t = (float)(acc[1] * (1.0 / (double)NVOX));

    SPos pa = make_spos(t, y0t, x0t, 3);
    const bool hasB = (t + 256) < NSP;
    SPos pb = make_spos(hasB ? (t + 256) : 0, y0t, x0t, 3);
    const int ty = t >> 4, tx = t & 15;

    f4 Ap[3], Bp[3], At[3], Bt[3];
#pragma unroll
    for (int q = 0; q < 3; ++q) {
        Ap[q] = (f4)0.0f; Bp[q] = (f4)0.0f;
        At[q] = (f4)0.0f; Bt[q] = (f4)0.0f;
    }
    float lsum = 0.0f;

    for (int tz = z0 - 1; tz <= z0 + CHZ; ++tz) {
        int zq = clampi(tz);
        int zc = zq * HW, zm = clampi(zq - 2) * HW, zp = clampi(zq + 2) * HW;
        stage_xsum(ip, zm, zc, zp, pa, Xp);
        stage_xsum(tp, zm, zc, zp, pa, Xt);
        if (hasB) {
            stage_xsum(ip, zm, zc, zp, pb, Xp);
            stage_xsum(tp, zm, zc, zp, pb, Xt);
        }
        __syncthreads();

        f4 qp[3], qt[3];
        box3y(Xp, ty, tx, qp);
        box3y(Xt, ty, tx, qt);
        __syncthreads();

        int ze = tz - 1;
        if (ze >= z0) {
            f4 vp[3], vt[3];
#pragma unroll
            for (int q = 0; q < 3; ++q) {
                vp[q] = Ap[q] + qp[q];
                vt[q] = At[q] + qt[q];
            }
            float mnp = min12(vp), smp = sum12(vp);
            float mnt = min12(vt), smt = sum12(vt);
            float varp = smp * (1.0f / 12.0f) - mnp;
            varp = fminf(fmaxf(varp, m_p * 0.001f), m_p * 1000.0f);
            float invp = -1.0f / varp;
            float vart = smt * (1.0f / 12.0f) - mnt;
            vart = fminf(fmaxf(vart, m_t * 0.001f), m_t * 1000.0f);
            float invt = -1.0f / vart;

            float a = 0.0f;
#pragma unroll
            for (int q = 0; q < 3; ++q)
#pragma unroll
                for (int i = 0; i < 4; ++i) {
                    float ep = __expf((vp[q][i] - mnp) * invp);
                    float et = __expf((vt[q][i] - mnt) * invt);
                    float dd = ep - et;
                    a += dd * dd;
                }
            lsum += a;
        }
#pragma unroll
        for (int q = 0; q < 3; ++q) {
            Ap[q] = Bp[q] + qp[q]; Bp[q] = qp[q];
            At[q] = Bt[q] + qt[q]; Bt[q] = qt[q];
        }
    }

    block_reduce_atomic(lsum, loss_sum);
}

__global__ void finalize_kernel(const double* __restrict__ acc,
                                const unsigned* __restrict__ keys,
                                float* __restrict__ out) {
    double l = (keys[4] == 0u) ? acc[2] : acc[3];
    out[0] = (float)(l * (1.0 / LOSS_COUNT));
}

extern "C" void kernel_launch(void* const* d_in, const int* in_sizes, int n_in,
                              void* d_out, int out_size, void* d_ws, size_t ws_size,
                              hipStream_t stream) {
    const float* pred = (const float*)d_in[0];
    const float* targ = (const float*)d_in[1];
    float* out = (float*)d_out;
    double* acc = (double*)d_ws;
    unsigned* keys = (unsigned*)((char*)d_ws + 64);

    dim3 block(256);
    dim3 grid(128, 8);   // 64 tiles * 2 batch, 8 z-chunks of 16 = 1024 blocks

    void* args[] = {(void*)&pred, (void*)&targ, (void*)&acc, (void*)&keys, (void*)&out};
    hipError_t e = hipLaunchCooperativeKernel((void*)mono_kernel, grid, block,
                                              args, 0, stream);
    if (e != hipSuccess) {
        // cooperative launch unavailable: round-6 multi-kernel sequence
        init_kernel<<<1, 1, 0, stream>>>(acc, keys);
        fused_kernel<<<grid, block, 0, stream>>>(pred, targ, acc, keys);
        flag_kernel<<<1, 1, 0, stream>>>(acc, keys);
        loss_kernel<<<grid, block, 0, stream>>>(pred, targ, acc, keys, &acc[3]);
        finalize_kernel<<<1, 1, 0, stream>>>(acc, keys, out);
    }
}

// Round 8
// 197.778 us; speedup vs baseline: 2.6250x; 2.6250x over previous
//
#include <hip/hip_runtime.h>

// MIND-SSC loss, N=2, C=1, D=H=W=128, radius=1, dilation=2.
// Round 8: round-6 fused kernel + last-block-done combine (no cooperative
// launch — round 7 showed grid.sync costs ~350 us at this grid size).
// Graph = memset(256B) + fused_kernel + loss_kernel(early-exit when clean).
//  - fused: x-folded staging, pred/targ packed float2, y-box from LDS,
//    z-box register ring; unclipped loss + var sums + var min/max
//  - per-block partials -> slots (agent-scope atomics); last finishing block
//    combines, computes m, exact clip-binding test, writes out when clean
//  - loss_kernel: full clipped recompute, only runs if the clip binds
//  - nested clamps preserved exactly; /27 dropped (exact: scale-invariant)

#define DIM 128
#define HW (128 * 128)
#define DHW (128 * 128 * 128)
#define NVOX (2 * DHW)
#define LOSS_COUNT (2.0 * 12.0 * DHW)

#define TS   16                   // tile side (y and x)
#define SY   18                   // xsum rows incl. y halo
#define NSP  (SY * TS)            // 288 xsum positions
#define CHZ  16                   // z-chunk per block
#define PSTR 7                    // f4 stride per position (6 used + 1 pad)
#define NBLK 1024                 // 128 x 8 grid

typedef float f4 __attribute__((ext_vector_type(4)));
typedef float f2 __attribute__((ext_vector_type(2)));

struct Header {                   // at d_ws+0, zeroed by memset each call
    unsigned counter0;            // fused completion counter
    unsigned counter1;            // dirty-path completion counter
    unsigned flag;                // 1 = clip binds (dirty)
    float m_p, m_t;
    unsigned pad;
    double acc_clip;              // clipped loss accumulator (dirty path)
};

struct Partial {                  // per-block slot at d_ws+256
    double vsump, vsumt, lsum;
    float mnp, mxp, mnt, mxt;
    float pad[6];                 // 64 B total
};

__device__ __forceinline__ int clampi(int v) {
    v = v < 0 ? 0 : v;
    return v > 127 ? 127 : v;
}

struct SPos {
    int y0, ym, yp;          // row offsets * DIM
    int cx[3], cm[3], cp[3]; // per-wx tap columns
    int woff;                // f4 index in LDS
};

__device__ __forceinline__ SPos make_spos(int p, int y0t, int x0t, int stride) {
    SPos q;
    int py = p >> 4, px = p & 15;
    int gy = clampi(y0t - 1 + py);
    int gx = x0t + px;
    q.y0 = gy * DIM; q.ym = clampi(gy - 2) * DIM; q.yp = clampi(gy + 2) * DIM;
#pragma unroll
    for (int wx = 0; wx < 3; ++wx) {
        int c = clampi(gx + wx - 1);   // box tap clamp (outer pad)
        q.cx[wx] = c;
        q.cm[wx] = clampi(c - 2);      // dilation clamp (inner pad)
        q.cp[wx] = clampi(c + 2);
    }
    q.woff = p * stride;
    return q;
}

// xsum for BOTH images at this position (packed f2); writes 6 f4.
__device__ __forceinline__ void stage_pair(const float* __restrict__ ip,
                                           const float* __restrict__ tp,
                                           int zm, int zc, int zp,
                                           const SPos& q, f4* __restrict__ X) {
    const int r0 = zm + q.y0, r1 = zc + q.y0, r2 = zc + q.ym;
    const int r3 = zc + q.yp, r4 = zp + q.y0;
    f2 acc[12];
#pragma unroll
    for (int c = 0; c < 12; ++c) acc[c] = (f2)0.0f;
#pragma unroll
    for (int wx = 0; wx < 3; ++wx) {
        int o0 = r0 + q.cx[wx];
        int o1 = r1 + q.cm[wx];
        int o2 = r2 + q.cx[wx];
        int o3 = r1 + q.cp[wx];
        int o4 = r4 + q.cx[wx];
        int o5 = r3 + q.cx[wx];
        f2 s0 = {ip[o0], tp[o0]};
        f2 s1 = {ip[o1], tp[o1]};
        f2 s2 = {ip[o2], tp[o2]};
        f2 s3 = {ip[o3], tp[o3]};
        f2 s4 = {ip[o4], tp[o4]};
        f2 s5 = {ip[o5], tp[o5]};
        f2 d;
        d = s1 - s0; acc[0]  += d * d;
        d = s2 - s0; acc[1]  += d * d;
        d = s2 - s1; acc[2]  += d * d;
        d = s3 - s0; acc[3]  += d * d;
        d = s3 - s2; acc[4]  += d * d;
        d = s4 - s1; acc[5]  += d * d;
        d = s4 - s2; acc[6]  += d * d;
        d = s4 - s3; acc[7]  += d * d;
        d = s5 - s0; acc[8]  += d * d;
        d = s5 - s1; acc[9]  += d * d;
        d = s5 - s3; acc[10] += d * d;
        d = s5 - s4; acc[11] += d * d;
    }
#pragma unroll
    for (int k = 0; k < 6; ++k) {
        f4 w;
        w.x = acc[2 * k].x;     w.y = acc[2 * k].y;
        w.z = acc[2 * k + 1].x; w.w = acc[2 * k + 1].y;
        X[q.woff + k] = w;
    }
}

__device__ __forceinline__ void box3y_pair(const f4* __restrict__ X,
                                           int ty, int tx, f4 q[6]) {
    int b0 = ((ty + 0) * TS + tx) * PSTR;
    int b1 = ((ty + 1) * TS + tx) * PSTR;
    int b2 = ((ty + 2) * TS + tx) * PSTR;
#pragma unroll
    for (int k = 0; k < 6; ++k)
        q[k] = X[b0 + k] + X[b1 + k] + X[b2 + k];
}

// single-image variants (clipped fallback path)
__device__ __forceinline__ void stage_xsum(const float* __restrict__ im,
                                           int zm, int zc, int zp,
                                           const SPos& q, f4* __restrict__ P) {
    const int r0 = zm + q.y0, r1 = zc + q.y0, r2 = zc + q.ym;
    const int r3 = zc + q.yp, r4 = zp + q.y0;
    f4 a = (f4)0.0f, b = (f4)0.0f, c = (f4)0.0f;
#pragma unroll
    for (int wx = 0; wx < 3; ++wx) {
        float s0 = im[r0 + q.cx[wx]];
        float s1 = im[r1 + q.cm[wx]];
        float s2 = im[r2 + q.cx[wx]];
        float s3 = im[r1 + q.cp[wx]];
        float s4 = im[r4 + q.cx[wx]];
        float s5 = im[r3 + q.cx[wx]];
        float d;
        d = s1 - s0; a.x += d * d;
        d = s2 - s0; a.y += d * d;
        d = s2 - s1; a.z += d * d;
        d = s3 - s0; a.w += d * d;
        d = s3 - s2; b.x += d * d;
        d = s4 - s1; b.y += d * d;
        d = s4 - s2; b.z += d * d;
        d = s4 - s3; b.w += d * d;
        d = s5 - s0; c.x += d * d;
        d = s5 - s1; c.y += d * d;
        d = s5 - s3; c.z += d * d;
        d = s5 - s4; c.w += d * d;
    }
    P[q.woff + 0] = a;
    P[q.woff + 1] = b;
    P[q.woff + 2] = c;
}

__device__ __forceinline__ void box3y(const f4* __restrict__ P,
                                      int ty, int tx, f4 q[3]) {
    int base = (ty * TS + tx) * 3;
#pragma unroll
    for (int k = 0; k < 3; ++k)
        q[k] = P[base + k] + P[base + TS * 3 + k] + P[base + 2 * TS * 3 + k];
}

__device__ __forceinline__ float min12(const f4 v[3]) {
    float mn = v[0][0];
#pragma unroll
    for (int i = 0; i < 4; ++i)
        mn = fminf(mn, fminf(v[0][i], fminf(v[1][i], v[2][i])));
    return mn;
}
__device__ __forceinline__ float sum12(const f4 v[3]) {
    float sm = 0.0f;
#pragma unroll
    for (int i = 0; i < 4; ++i)
        sm += v[0][i] + v[1][i] + v[2][i];
    return sm;
}

// ======================  fused kernel + tail combine  ======================

__global__ __launch_bounds__(256, 4) void fused_kernel(const float* __restrict__ pred,
                                                       const float* __restrict__ targ,
                                                       Header* __restrict__ hdr,
                                                       Partial* __restrict__ parts,
                                                       float* __restrict__ out) {
    __shared__ f4 X[NSP * PSTR];

    const int t = threadIdx.x;
    const int tile = blockIdx.x & 63, n = blockIdx.x >> 6;
    const int x0t = (tile & 7) * TS, y0t = (tile >> 3) * TS;
    const int z0 = blockIdx.y * CHZ;
    const int bid = blockIdx.y * gridDim.x + blockIdx.x;
    const float* ip = pred + (size_t)n * DHW;
    const float* tp = targ + (size_t)n * DHW;

    SPos pa = make_spos(t, y0t, x0t, PSTR);
    const bool hasB = (t + 256) < NSP;
    SPos pb = make_spos(hasB ? (t + 256) : 0, y0t, x0t, PSTR);
    const int ty = t >> 4, tx = t & 15;

    f4 A[6], B[6];
#pragma unroll
    for (int k = 0; k < 6; ++k) { A[k] = (f4)0.0f; B[k] = (f4)0.0f; }

    float vsump = 0.0f, vsumt = 0.0f, lsum = 0.0f;
    float locmnp = 1e30f, locmxp = -1e30f, locmnt = 1e30f, locmxt = -1e30f;

    for (int tz = z0 - 1; tz <= z0 + CHZ; ++tz) {
        int zq = clampi(tz);
        int zc = zq * HW, zm = clampi(zq - 2) * HW, zp = clampi(zq + 2) * HW;
        stage_pair(ip, tp, zm, zc, zp, pa, X);
        if (hasB) stage_pair(ip, tp, zm, zc, zp, pb, X);
        __syncthreads();

        f4 q[6];
        box3y_pair(X, ty, tx, q);
        __syncthreads();

        int ze = tz - 1;
        if (ze >= z0) {
            f4 v[6];
#pragma unroll
            for (int k = 0; k < 6; ++k) v[k] = A[k] + q[k];

            float mnp = v[0][0], mnt = v[0][1];
            float smp = 0.0f, smt = 0.0f;
#pragma unroll
            for (int c = 0; c < 12; ++c) {
                float pv = v[c >> 1][(c & 1) * 2];
                float tv = v[c >> 1][(c & 1) * 2 + 1];
                mnp = fminf(mnp, pv); smp += pv;
                mnt = fminf(mnt, tv); smt += tv;
            }
            float varp = smp * (1.0f / 12.0f) - mnp;
            float vart = smt * (1.0f / 12.0f) - mnt;
            vsump += varp; vsumt += vart;
            locmnp = fminf(locmnp, varp); locmxp = fmaxf(locmxp, varp);
            locmnt = fminf(locmnt, vart); locmxt = fmaxf(locmxt, vart);

            float invp = -1.0f / varp;   // unclipped; validated by tail block
            float invt = -1.0f / vart;
            float la = 0.0f;
#pragma unroll
            for (int c = 0; c < 12; ++c) {
                float pv = v[c >> 1][(c & 1) * 2];
                float tv = v[c >> 1][(c & 1) * 2 + 1];
                float ep = __expf((pv - mnp) * invp);
                float et = __expf((tv - mnt) * invt);
                float dd = ep - et;
                la += dd * dd;
            }
            lsum += la;
        }
#pragma unroll
        for (int k = 0; k < 6; ++k) { A[k] = B[k] + q[k]; B[k] = q[k]; }
    }

    // ---- per-block reduce of 7 quantities to thread 0 ----
#pragma unroll
    for (int off = 32; off > 0; off >>= 1) {
        vsump += __shfl_down(vsump, off, 64);
        vsumt += __shfl_down(vsumt, off, 64);
        lsum  += __shfl_down(lsum,  off, 64);
        locmnp = fminf(locmnp, __shfl_down(locmnp, off, 64));
        locmxp = fmaxf(locmxp, __shfl_down(locmxp, off, 64));
        locmnt = fminf(locmnt, __shfl_down(locmnt, off, 64));
        locmxt = fmaxf(locmxt, __shfl_down(locmxt, off, 64));
    }
    __shared__ float rs[4][7];
    __shared__ int s_tail;
    {
        int lane = t & 63, wid = t >> 6;
        if (lane == 0) {
            rs[wid][0] = vsump; rs[wid][1] = vsumt; rs[wid][2] = lsum;
            rs[wid][3] = locmnp; rs[wid][4] = locmxp;
            rs[wid][5] = locmnt; rs[wid][6] = locmxt;
        }
    }
    __syncthreads();
    if (t == 0) {
        double d0 = (double)rs[0][0] + rs[1][0] + rs[2][0] + rs[3][0];
        double d1 = (double)rs[0][1] + rs[1][1] + rs[2][1] + rs[3][1];
        double d2 = (double)rs[0][2] + rs[1][2] + rs[2][2] + rs[3][2];
        float a = fminf(fminf(rs[0][3], rs[1][3]), fminf(rs[2][3], rs[3][3]));
        float b = fmaxf(fmaxf(rs[0][4], rs[1][4]), fmaxf(rs[2][4], rs[3][4]));
        float c = fminf(fminf(rs[0][5], rs[1][5]), fminf(rs[2][5], rs[3][5]));
        float d = fmaxf(fmaxf(rs[0][6], rs[1][6]), fmaxf(rs[2][6], rs[3][6]));
        Partial* p = &parts[bid];
        __hip_atomic_store(&p->vsump, d0, __ATOMIC_RELAXED, __HIP_MEMORY_SCOPE_AGENT);
        __hip_atomic_store(&p->vsumt, d1, __ATOMIC_RELAXED, __HIP_MEMORY_SCOPE_AGENT);
        __hip_atomic_store(&p->lsum,  d2, __ATOMIC_RELAXED, __HIP_MEMORY_SCOPE_AGENT);
        __hip_atomic_store(&p->mnp, a, __ATOMIC_RELAXED, __HIP_MEMORY_SCOPE_AGENT);
        __hip_atomic_store(&p->mxp, b, __ATOMIC_RELAXED, __HIP_MEMORY_SCOPE_AGENT);
        __hip_atomic_store(&p->mnt, c, __ATOMIC_RELAXED, __HIP_MEMORY_SCOPE_AGENT);
        __hip_atomic_store(&p->mxt, d, __ATOMIC_RELAXED, __HIP_MEMORY_SCOPE_AGENT);
        unsigned old = __hip_atomic_fetch_add(&hdr->counter0, 1u,
                                              __ATOMIC_ACQ_REL, __HIP_MEMORY_SCOPE_AGENT);
        s_tail = (old == NBLK - 1) ? 1 : 0;
    }
    __syncthreads();

    // ---- last-finishing block: combine all partials, flag, maybe finalize ----
    if (s_tail) {
        double vp = 0.0, vt = 0.0, ls = 0.0;
        float mnp = 1e30f, mxp = -1e30f, mnt = 1e30f, mxt = -1e30f;
        for (int b = t; b < NBLK; b += 256) {
            const Partial* p = &parts[b];
            vp += __hip_atomic_load(&p->vsump, __ATOMIC_RELAXED, __HIP_MEMORY_SCOPE_AGENT);
            vt += __hip_atomic_load(&p->vsumt, __ATOMIC_RELAXED, __HIP_MEMORY_SCOPE_AGENT);
            ls += __hip_atomic_load(&p->lsum,  __ATOMIC_RELAXED, __HIP_MEMORY_SCOPE_AGENT);
            mnp = fminf(mnp, __hip_atomic_load(&p->mnp, __ATOMIC_RELAXED, __HIP_MEMORY_SCOPE_AGENT));
            mxp = fmaxf(mxp, __hip_atomic_load(&p->mxp, __ATOMIC_RELAXED, __HIP_MEMORY_SCOPE_AGENT));
            mnt = fminf(mnt, __hip_atomic_load(&p->mnt, __ATOMIC_RELAXED, __HIP_MEMORY_SCOPE_AGENT));
            mxt = fmaxf(mxt, __hip_atomic_load(&p->mxt, __ATOMIC_RELAXED, __HIP_MEMORY_SCOPE_AGENT));
        }
#pragma unroll
        for (int off = 32; off > 0; off >>= 1) {
            vp += __shfl_down(vp, off, 64);
            vt += __shfl_down(vt, off, 64);
            ls += __shfl_down(ls, off, 64);
            mnp = fminf(mnp, __shfl_down(mnp, off, 64));
            mxp = fmaxf(mxp, __shfl_down(mxp, off, 64));
            mnt = fminf(mnt, __shfl_down(mnt, off, 64));
            mxt = fmaxf(mxt, __shfl_down(mxt, off, 64));
        }
        __shared__ double rd[4][3];
        __shared__ float rf[4][4];
        int lane = t & 63, wid = t >> 6;
        if (lane == 0) {
            rd[wid][0] = vp; rd[wid][1] = vt; rd[wid][2] = ls;
            rf[wid][0] = mnp; rf[wid][1] = mxp; rf[wid][2] = mnt; rf[wid][3] = mxt;
        }
        __syncthreads();
        if (t == 0) {
            double VP = rd[0][0] + rd[1][0] + rd[2][0] + rd[3][0];
            double VT = rd[0][1] + rd[1][1] + rd[2][1] + rd[3][1];
            double LS = rd[0][2] + rd[1][2] + rd[2][2] + rd[3][2];
            float MNP = fminf(fminf(rf[0][0], rf[1][0]), fminf(rf[2][0], rf[3][0]));
            float MXP = fmaxf(fmaxf(rf[0][1], rf[1][1]), fmaxf(rf[2][1], rf[3][1]));
            float MNT = fminf(fminf(rf[0][2], rf[1][2]), fminf(rf[2][2], rf[3][2]));
            float MXT = fmaxf(fmaxf(rf[0][3], rf[1][3]), fmaxf(rf[2][3], rf[3][3]));
            float m_p = (float)(VP * (1.0 / (double)NVOX));
            float m_t = (float)(VT * (1.0 / (double)NVOX));
            // clip leaves v unchanged iff lo <= v <= hi (same fp exprs as fallback)
            bool clean = (MNP >= m_p * 0.001f) && (MXP <= m_p * 1000.0f) &&
                         (MNT >= m_t * 0.001f) && (MXT <= m_t * 1000.0f);
            hdr->m_p = m_p;
            hdr->m_t = m_t;
            __hip_atomic_store(&hdr->acc_clip, 0.0, __ATOMIC_RELAXED, __HIP_MEMORY_SCOPE_AGENT);
            __hip_atomic_store(&hdr->flag, clean ? 0u : 1u,
                               __ATOMIC_RELEASE, __HIP_MEMORY_SCOPE_AGENT);
            if (clean) out[0] = (float)(LS * (1.0 / LOSS_COUNT));
        }
    }
}

// =================  clipped fallback (only if clip binds)  =================

__global__ __launch_bounds__(256, 4) void loss_kernel(const float* __restrict__ pred,
                                                      const float* __restrict__ targ,
                                                      Header* __restrict__ hdr,
                                                      float* __restrict__ out) {
    if (__hip_atomic_load(&hdr->flag, __ATOMIC_ACQUIRE, __HIP_MEMORY_SCOPE_AGENT) == 0u)
        return;   // block-uniform; expected path

    __shared__ f4 Xp[NSP * 3];
    __shared__ f4 Xt[NSP * 3];
    const int t = threadIdx.x;
    const int tile = blockIdx.x & 63, n = blockIdx.x >> 6;
    const int x0t = (tile & 7) * TS, y0t = (tile >> 3) * TS;
    const int z0 = blockIdx.y * CHZ;
    const float* ip = pred + (size_t)n * DHW;
    const float* tp = targ + (size_t)n * DHW;

    const float m_p = hdr->m_p;
    const float m_t = hdr->m_t;

    SPos pa = make_spos(t, y0t, x0t, 3);
    const bool hasB = (t + 256) < NSP;
    SPos pb = make_spos(hasB ? (t + 256) : 0, y0t, x0t, 3);
    const int ty = t >> 4, tx = t & 15;

    f4 Ap[3], Bp[3], At[3], Bt[3];
#pragma unroll
    for (int q = 0; q < 3; ++q) {
        Ap[q] = (f4)0.0f; Bp[q] = (f4)0.0f;
        At[q] = (f4)0.0f; Bt[q] = (f4)0.0f;
    }
    float lsum = 0.0f;

    for (int tz = z0 - 1; tz <= z0 + CHZ; ++tz) {
        int zq = clampi(tz);
        int zc = zq * HW, zm = clampi(zq - 2) * HW, zp = clampi(zq + 2) * HW;
        stage_xsum(ip, zm, zc, zp, pa, Xp);
        stage_xsum(tp, zm, zc, zp, pa, Xt);
        if (hasB) {
            stage_xsum(ip, zm, zc, zp, pb, Xp);
            stage_xsum(tp, zm, zc, zp, pb, Xt);
        }
        __syncthreads();

        f4 qp[3], qt[3];
        box3y(Xp, ty, tx, qp);
        box3y(Xt, ty, tx, qt);
        __syncthreads();

        int ze = tz - 1;
        if (ze >= z0) {
            f4 vp[3], vt[3];
#pragma unroll
            for (int q = 0; q < 3; ++q) {
                vp[q] = Ap[q] + qp[q];
                vt[q] = At[q] + qt[q];
            }
            float mnp = min12(vp), smp = sum12(vp);
            float mnt = min12(vt), smt = sum12(vt);
            float varp = smp * (1.0f / 12.0f) - mnp;
            varp = fminf(fmaxf(varp, m_p * 0.001f), m_p * 1000.0f);
            float invp = -1.0f / varp;
            float vart = smt * (1.0f / 12.0f) - mnt;
            vart = fminf(fmaxf(vart, m_t * 0.001f), m_t * 1000.0f);
            float invt = -1.0f / vart;

            float a = 0.0f;
#pragma unroll
            for (int q = 0; q < 3; ++q)
#pragma unroll
                for (int i = 0; i < 4; ++i) {
                    float ep = __expf((vp[q][i] - mnp) * invp);
                    float et = __expf((vt[q][i] - mnt) * invt);
                    float dd = ep - et;
                    a += dd * dd;
                }
            lsum += a;
        }
#pragma unroll
        for (int q = 0; q < 3; ++q) {
            Ap[q] = Bp[q] + qp[q]; Bp[q] = qp[q];
            At[q] = Bt[q] + qt[q]; Bt[q] = qt[q];
        }
    }

    // block reduce -> device accumulate -> last block writes out
#pragma unroll
    for (int off = 32; off > 0; off >>= 1)
        lsum += __shfl_down(lsum, off, 64);
    __shared__ float red[4];
    int lane = t & 63, wid = t >> 6;
    if (lane == 0) red[wid] = lsum;
    __syncthreads();
    if (t == 0) {
        double tt = (double)red[0] + red[1] + red[2] + red[3];
        atomicAdd(&hdr->acc_clip, tt);
        unsigned old = __hip_atomic_fetch_add(&hdr->counter1, 1u,
                                              __ATOMIC_ACQ_REL, __HIP_MEMORY_SCOPE_AGENT);
        if (old == NBLK - 1) {
            double l = __hip_atomic_load(&hdr->acc_clip, __ATOMIC_RELAXED,
                                         __HIP_MEMORY_SCOPE_AGENT);
            out[0] = (float)(l * (1.0 / LOSS_COUNT));
        }
    }
}

extern "C" void kernel_launch(void* const* d_in, const int* in_sizes, int n_in,
                              void* d_out, int out_size, void* d_ws, size_t ws_size,
                              hipStream_t stream) {
    const float* pred = (const float*)d_in[0];
    const float* targ = (const float*)d_in[1];
    float* out = (float*)d_out;
    Header* hdr = (Header*)d_ws;
    Partial* parts = (Partial*)((char*)d_ws + 256);

    hipMemsetAsync(d_ws, 0, 256, stream);

    dim3 block(256);
    dim3 grid(128, 8);   // 64 tiles * 2 batch, 8 z-chunks of 16 = 1024 blocks
    fused_kernel<<<grid, block, 0, stream>>>(pred, targ, hdr, parts, out);
    loss_kernel<<<grid, block, 0, stream>>>(pred, targ, hdr, out);
}